// Round 5
// baseline (719.817 us; speedup 1.0000x reference)
//
#include <hip/hip_runtime.h>

// ---------------------------------------------------------------------------
// GraphTrajSimEncoder on MI355X — round 11.
// R10 post-mortem: k_agg is at the random-gather path wall (~4.2 TB/s: four
// structurally different impls converge 117-125us; pad cut didn't move FETCH
// because pad gathers hit the L2-hot row 0). R11 attacks the non-agg pool:
//  - scanA/B/C replaced by 1-kernel bump allocator (CSR region order is
//    irrelevant; LLVM atomic-optimizer coalesces the hot counter)
//  - GEMM grids reordered so blocks sharing an A-tile are launch-adjacent
//    (gemm_bt: (2,2,Mb); gemm_dual: (2,Mb)) -> A re-reads become L2/L3 hits
//  - k_agg unchanged except e1 derived from cnt (off is now just starts)
// ---------------------------------------------------------------------------

using bf16x8  = __attribute__((ext_vector_type(8))) __bf16;
using floatx4 = __attribute__((ext_vector_type(4))) float;
using f32x2   = __attribute__((ext_vector_type(2))) float;

__device__ __forceinline__ unsigned short f2b(float f) {
    unsigned u = __float_as_uint(f);
    return (unsigned short)((u + 0x7FFFu + ((u >> 16) & 1u)) >> 16);
}
__device__ __forceinline__ unsigned short f2h(float f) {
    _Float16 h = (_Float16)f;
    return __builtin_bit_cast(unsigned short, h);
}
__device__ __forceinline__ float h2f(unsigned short u) {
    return (float)__builtin_bit_cast(_Float16, u);
}

// ---------------- fused front kernel ----------------
// segment 0: [0, E)            set-0 degree count atomics
// segment 1: [E, 2E)           set-1 degree count atomics
// segment 2: [2E, 2E+NXC)      xc bf16 conversion, 8 elems/thread
// segment 3: [.., +TOTW)       weight conversions
__global__ void k_front(
    const int* __restrict__ col0, const int* __restrict__ col1, int E,
    int* __restrict__ cnt0, int* __restrict__ cnt1,
    const float* __restrict__ x, const float* __restrict__ pe,
    unsigned short* __restrict__ xc,
    const float* __restrict__ Wn1, const float* __restrict__ Wn2,
    const float* __restrict__ W11, const float* __restrict__ W12,
    const float* __restrict__ W21, const float* __restrict__ W22,
    const float* __restrict__ W31, const float* __restrict__ W32,
    const float* __restrict__ W41, const float* __restrict__ W42,
    unsigned short* __restrict__ wn0c, unsigned short* __restrict__ wn1c,
    unsigned short* __restrict__ wc0, unsigned short* __restrict__ wc1,
    unsigned short* __restrict__ wc2, unsigned short* __restrict__ wc3,
    int n, int F, int PEd, int KC, int KP) {
    int idx = blockIdx.x * 256 + threadIdx.x;
    if (idx < E) { atomicAdd(&cnt0[col0[idx]], 1); return; }
    idx -= E;
    if (idx < E) { atomicAdd(&cnt1[col1[idx]], 1); return; }
    idx -= E;
    const int CH = KP >> 3;
    const int NXC = n * CH;
    if (idx < NXC) {
        int i = idx / CH, c = idx - i * CH;
        int k = c << 3;
        uint4 o;
        if (k + 8 <= F) {
            const float4* px = (const float4*)(x + (size_t)i * F + k);
            float4 v0 = px[0];
            float4 v1 = px[1];
            o.x = (unsigned)f2b(v0.x) | ((unsigned)f2b(v0.y) << 16);
            o.y = (unsigned)f2b(v0.z) | ((unsigned)f2b(v0.w) << 16);
            o.z = (unsigned)f2b(v1.x) | ((unsigned)f2b(v1.y) << 16);
            o.w = (unsigned)f2b(v1.z) | ((unsigned)f2b(v1.w) << 16);
        } else if (k < KC) {
            const float* pp = pe + (size_t)i * PEd + (k - F);
            int rem = KC - k;
            float e0 = pp[0];
            float e1 = (1 < rem) ? pp[1] : 0.f;
            float e2 = (2 < rem) ? pp[2] : 0.f;
            float e3 = (3 < rem) ? pp[3] : 0.f;
            float e4 = (4 < rem) ? pp[4] : 0.f;
            float e5 = (5 < rem) ? pp[5] : 0.f;
            float e6 = (6 < rem) ? pp[6] : 0.f;
            float e7 = (7 < rem) ? pp[7] : 0.f;
            o.x = (unsigned)f2b(e0) | ((unsigned)f2b(e1) << 16);
            o.y = (unsigned)f2b(e2) | ((unsigned)f2b(e3) << 16);
            o.z = (unsigned)f2b(e4) | ((unsigned)f2b(e5) << 16);
            o.w = (unsigned)f2b(e6) | ((unsigned)f2b(e7) << 16);
        } else {
            o.x = o.y = o.z = o.w = 0u;
        }
        *(uint4*)(xc + (size_t)idx * 8) = o;
        return;
    }
    idx -= NXC;
    int npad = F * KP;
    if (idx < 2 * npad) {
        const float* W = (idx < npad) ? Wn1 : Wn2;
        unsigned short* Wc = (idx < npad) ? wn0c : wn1c;
        int t = (idx < npad) ? idx : idx - npad;
        int o = t / KP, k = t - o * KP;
        Wc[t] = f2b(k < KC ? W[(size_t)o * KC + k] : 0.0f);
        return;
    }
    int t = idx - 2 * npad;
    int seg = F * 512;
    if (t >= 4 * seg) return;
    int which = t / seg;
    int r = t - which * seg;
    const float* Wa = (which == 0) ? W11 : (which == 1) ? W21 : (which == 2) ? W31 : W41;
    const float* Wb = (which == 0) ? W12 : (which == 1) ? W22 : (which == 2) ? W32 : W42;
    unsigned short* Wc = (which == 0) ? wc0 : (which == 1) ? wc1 : (which == 2) ? wc2 : wc3;
    int o = r >> 9, k = r & 511;
    float v = (k < 256) ? Wa[(size_t)o * 256 + k] : Wb[(size_t)o * 256 + (k - 256)];
    Wc[r] = f2b(v);
}

// ---------------- CSR region allocation (bump allocator) ----------------
// Region order is irrelevant to correctness; LLVM's atomic optimizer turns the
// same-address varying-value atomicAdd into one wave-prefix + 1 atomic/wave.
// off[i] = region start (multiple of 4), cur[i] = edge write cursor,
// dinv[i] = rsqrt(deg+1). Region size = (cnt+1 self) padded to x4.
__global__ void k_alloc(
    const int* __restrict__ cnt0, const int* __restrict__ cnt1,
    int* __restrict__ tot,                       // tot[0], tot[1] zeroed
    int* __restrict__ off0, int* __restrict__ off1,
    float* __restrict__ dinv0, float* __restrict__ dinv1,
    int* __restrict__ cur0, int* __restrict__ cur1, int n) {
    int i = blockIdx.x * 256 + threadIdx.x;
    if (i >= n) return;
    const int* cnt = blockIdx.y ? cnt1 : cnt0;
    int* off = blockIdx.y ? off1 : off0;
    float* dinv = blockIdx.y ? dinv1 : dinv0;
    int* cur = blockIdx.y ? cur1 : cur0;
    int ci = cnt[i];
    int pad = (ci + 4) & ~3;
    int o = atomicAdd(&tot[blockIdx.y], pad);
    off[i] = o;
    cur[i] = o;
    dinv[i] = rsqrtf((float)(ci + 1));
}

// Fused CSR fill + self-loop/pad. Threads [0, EB) fill edges; [EB, EB+n) pad.
// Edge record: (src:u32, (fp16 w1)<<16 | fp16 w2). Self: w1=dinv^2, w2=1.
__global__ void k_fillpad(
    const int* __restrict__ ei0, const float* __restrict__ ea0,
    const int* __restrict__ ei1, const float* __restrict__ ea1,
    int E, int EB,
    const int* __restrict__ cnt0, const int* __restrict__ cnt1,
    const int* __restrict__ off0, const int* __restrict__ off1,
    const float* __restrict__ dinv0, const float* __restrict__ dinv1,
    int* __restrict__ cur0, int* __restrict__ cur1,
    uint2* __restrict__ rec0, uint2* __restrict__ rec1, int n) {
    const int s = blockIdx.y;
    const float* dinv = s ? dinv1 : dinv0;
    uint2* rec = s ? rec1 : rec0;
    int t = blockIdx.x * 256 + threadIdx.x;
    if (t < EB) {
        int e = t;
        if (e >= E) return;
        const int* ei = s ? ei1 : ei0;
        const float* ea = s ? ea1 : ea0;
        int* cur = s ? cur1 : cur0;
        int r = ei[e];          // source
        int c = ei[E + e];      // target
        float a = ea[e];
        float w2 = (a > 0.0f) ? fminf(rsqrtf(a), 1.0f) : 0.0f;
        float w1 = dinv[r] * dinv[c];
        int p = atomicAdd(&cur[c], 1);
        rec[p] = make_uint2((unsigned)r,
                            ((unsigned)f2h(w1) << 16) | (unsigned)f2h(w2));
    } else {
        int i = t - EB;
        if (i >= n) return;
        const int* cnt = s ? cnt1 : cnt0;
        const int* off = s ? off1 : off0;
        int ci = cnt[i];
        int p = off[i] + ci, pe = off[i] + ((ci + 4) & ~3);
        float di = dinv[i];
        rec[p++] = make_uint2((unsigned)i,
                              ((unsigned)f2h(di * di) << 16) | 0x3C00u);  // w2=1
        for (; p < pe; ++p) rec[p] = make_uint2(0u, 0u);
    }
}

// ---------------- CSR gather-aggregation v6 ----------------
// One wave per node, one 64-lane gather per record (8B/lane = 512B row).
// Records loaded as uint4 pairs (4 records / 2 loads). Packed f32 FMA.
// Self loop is a record; pads are (row0, w=0) (row 0 stays L2-hot: free-ish).
// No local arrays (R7 lesson), no pipeline (R9/R10 lesson: path-throughput
// wall ~4.2 TB/s, not latency/ILP). Output A[i] = [a1(256) | a2(256)] bf16.

#define AGG4(g, wsel)                                                         \
    do {                                                                      \
        float w1 = h2f((unsigned short)((wsel) >> 16));                       \
        float w2 = h2f((unsigned short)((wsel) & 0xFFFFu));                   \
        f32x2 w1v = {w1, w1};                                                 \
        f32x2 w2v = {w2, w2};                                                 \
        f32x2 v;                                                              \
        v.x = __uint_as_float((g).x << 16);                                   \
        v.y = __uint_as_float((g).x & 0xFFFF0000u);                           \
        c1a = __builtin_elementwise_fma(w1v, v, c1a);                         \
        c2a = __builtin_elementwise_fma(w2v, v, c2a);                         \
        v.x = __uint_as_float((g).y << 16);                                   \
        v.y = __uint_as_float((g).y & 0xFFFF0000u);                           \
        c1b = __builtin_elementwise_fma(w1v, v, c1b);                         \
        c2b = __builtin_elementwise_fma(w2v, v, c2b);                         \
    } while (0)

__global__ __launch_bounds__(256) void k_agg(
    const unsigned short* __restrict__ X0, const unsigned short* __restrict__ X1,
    const int* __restrict__ cnt0, const int* __restrict__ cnt1,
    const int* __restrict__ off0, const int* __restrict__ off1,
    const uint2* __restrict__ rec0, const uint2* __restrict__ rec1,
    unsigned short* __restrict__ A0, unsigned short* __restrict__ A1, int n) {
    const int s = blockIdx.y;
    const unsigned short* X = s ? X1 : X0;
    const int* cnt = s ? cnt1 : cnt0;
    const int* off = s ? off1 : off0;
    const uint2* rec = s ? rec1 : rec0;
    unsigned short* A = s ? A1 : A0;

    const int gw = (blockIdx.x * 256 + threadIdx.x) >> 6;
    const int lane = threadIdx.x & 63;
    if (gw >= n) return;

    const int e0 = __builtin_amdgcn_readfirstlane(off[gw]);
    const int cv = __builtin_amdgcn_readfirstlane(cnt[gw]);
    const uint2* X2 = (const uint2*)X;          // 4 bf16 per lane-chunk

    f32x2 c1a = {0.f, 0.f}, c1b = {0.f, 0.f};
    f32x2 c2a = {0.f, 0.f}, c2b = {0.f, 0.f};

    const uint4* recq = (const uint4*)(rec + e0);   // 1 uint4 = 2 records
    const int nit = ((cv + 4) & ~3) >> 2;           // 4 records / iter, >= 1
    #pragma unroll 2
    for (int it = 0; it < nit; ++it) {
        uint4 qa = recq[it * 2];
        uint4 qb = recq[it * 2 + 1];
        unsigned s0 = (unsigned)__builtin_amdgcn_readfirstlane(qa.x);
        unsigned s1 = (unsigned)__builtin_amdgcn_readfirstlane(qa.z);
        unsigned s2 = (unsigned)__builtin_amdgcn_readfirstlane(qb.x);
        unsigned s3 = (unsigned)__builtin_amdgcn_readfirstlane(qb.z);
        uint2 g0 = X2[(size_t)s0 * 64 + lane];
        uint2 g1 = X2[(size_t)s1 * 64 + lane];
        uint2 g2 = X2[(size_t)s2 * 64 + lane];
        uint2 g3 = X2[(size_t)s3 * 64 + lane];
        AGG4(g0, qa.y);
        AGG4(g1, qa.w);
        AGG4(g2, qb.y);
        AGG4(g3, qb.w);
    }

    uint2 o1, o2;
    o1.x = (unsigned)f2b(c1a.x) | ((unsigned)f2b(c1a.y) << 16);
    o1.y = (unsigned)f2b(c1b.x) | ((unsigned)f2b(c1b.y) << 16);
    o2.x = (unsigned)f2b(c2a.x) | ((unsigned)f2b(c2a.y) << 16);
    o2.y = (unsigned)f2b(c2b.x) | ((unsigned)f2b(c2b.y) << 16);
    *(uint2*)(A + (size_t)gw * 512 + lane * 4) = o1;
    *(uint2*)(A + (size_t)gw * 512 + 256 + lane * 4) = o2;
}

// ---------------- bf16 MFMA GEMM kernels ----------------
#define GLL(g, l) \
    __builtin_amdgcn_global_load_lds((__attribute__((address_space(1))) void*)(g), \
                                     (__attribute__((address_space(3))) void*)(l), 16, 0, 0)

// node-transform GEMM: C[M][Nc] = A[M][K] @ B[Nc][K]^T, bf16 out.
// Grid (2, 2, Mb): x = column tile, y = B/out select, z = row tile, so the 4
// blocks sharing an A-tile are launch-adjacent (A re-reads hit L2/L3).
__global__ __launch_bounds__(256) void gemm_bt(
    const unsigned short* __restrict__ A,
    const unsigned short* __restrict__ B0, const unsigned short* __restrict__ B1,
    int M, int K, int Nc,
    unsigned short* __restrict__ outH0, unsigned short* __restrict__ outH1) {
    const unsigned short* B = blockIdx.y ? B1 : B0;
    unsigned short* outH = blockIdx.y ? outH1 : outH0;

    __shared__ __align__(16) unsigned short sA[128 * 32];
    __shared__ __align__(16) unsigned short sB[128 * 32];
    const int tid = threadIdx.x;
    const int lane = tid & 63;
    const int wave = tid >> 6;
    const int bm = blockIdx.z * 128;
    const int bn = blockIdx.x * 128;

    const int r0 = wave * 32 + (lane >> 2);
    const int kcol = (lane & 3) * 8;
    const int ga0 = min(bm + r0, M - 1);
    const int ga1 = min(bm + r0 + 16, M - 1);
    const int gb0 = min(bn + r0, Nc - 1);
    const int gb1 = min(bn + r0 + 16, Nc - 1);
    const unsigned short* pa0 = A + (size_t)ga0 * K + kcol;
    const unsigned short* pa1 = A + (size_t)ga1 * K + kcol;
    const unsigned short* pb0 = B + (size_t)gb0 * K + kcol;
    const unsigned short* pb1 = B + (size_t)gb1 * K + kcol;
    unsigned short* la0 = &sA[wave * 1024];
    unsigned short* la1 = &sA[wave * 1024 + 512];
    unsigned short* lb0 = &sB[wave * 1024];
    unsigned short* lb1 = &sB[wave * 1024 + 512];

    floatx4 acc[4][4];
    #pragma unroll
    for (int i = 0; i < 4; i++)
        #pragma unroll
        for (int j = 0; j < 4; j++) acc[i][j] = (floatx4){0.f, 0.f, 0.f, 0.f};

    const int mbase = (wave & 1) * 64 + (lane & 15);
    const int nbase = (wave >> 1) * 64 + (lane & 15);
    const int koff = (lane >> 4) * 8;

    for (int kk = 0; kk < K; kk += 32) {
        GLL(pa0 + kk, la0);
        GLL(pa1 + kk, la1);
        GLL(pb0 + kk, lb0);
        GLL(pb1 + kk, lb1);
        __syncthreads();
        bf16x8 af[4], bf[4];
        #pragma unroll
        for (int mi = 0; mi < 4; mi++)
            af[mi] = *(const bf16x8*)&sA[(mbase + mi * 16) * 32 + koff];
        #pragma unroll
        for (int ni = 0; ni < 4; ni++)
            bf[ni] = *(const bf16x8*)&sB[(nbase + ni * 16) * 32 + koff];
        #pragma unroll
        for (int mi = 0; mi < 4; mi++)
            #pragma unroll
            for (int ni = 0; ni < 4; ni++)
                acc[mi][ni] = __builtin_amdgcn_mfma_f32_16x16x32_bf16(
                    af[mi], bf[ni], acc[mi][ni], 0, 0, 0);
        __syncthreads();
    }

    const int crow = bm + (wave & 1) * 64 + (lane >> 4) * 4;
    const int ccol = bn + (wave >> 1) * 64 + (lane & 15);
    #pragma unroll
    for (int mi = 0; mi < 4; mi++)
        #pragma unroll
        for (int ni = 0; ni < 4; ni++)
            #pragma unroll
            for (int r = 0; r < 4; r++) {
                int row = crow + mi * 16 + r;
                if (row >= M) continue;
                int col = ccol + ni * 16;
                outH[(size_t)row * Nc + col] = f2b(acc[mi][ni][r]);
            }
}

// dual GEMM: C = 0.5*relu(A0@B0^T) + 0.5*relu(A1@B1^T); out f32 or bf16.
// Grid (2, Mb): x = column tile, y = row tile (same-A blocks launch-adjacent).
__global__ __launch_bounds__(256) void gemm_dual(
    const unsigned short* __restrict__ A0, const unsigned short* __restrict__ B0,
    const unsigned short* __restrict__ A1, const unsigned short* __restrict__ B1,
    int M, int K, int Nc,
    float* __restrict__ outF, unsigned short* __restrict__ outH, float alpha) {
    __shared__ __align__(16) unsigned short sA[128 * 32];
    __shared__ __align__(16) unsigned short sB[128 * 32];
    const int tid = threadIdx.x;
    const int lane = tid & 63;
    const int wave = tid >> 6;
    const int bm = blockIdx.y * 128;
    const int bn = blockIdx.x * 128;

    const int r0 = wave * 32 + (lane >> 2);
    const int kcol = (lane & 3) * 8;
    const int ga0 = min(bm + r0, M - 1);
    const int ga1 = min(bm + r0 + 16, M - 1);
    const int gb0 = min(bn + r0, Nc - 1);
    const int gb1 = min(bn + r0 + 16, Nc - 1);
    unsigned short* la0 = &sA[wave * 1024];
    unsigned short* la1 = &sA[wave * 1024 + 512];
    unsigned short* lb0 = &sB[wave * 1024];
    unsigned short* lb1 = &sB[wave * 1024 + 512];

    const int mbase = (wave & 1) * 64 + (lane & 15);
    const int nbase = (wave >> 1) * 64 + (lane & 15);
    const int koff = (lane >> 4) * 8;

    floatx4 acc[4][4], res[4][4];

    #pragma unroll
    for (int pass = 0; pass < 2; pass++) {
        const unsigned short* A = pass ? A1 : A0;
        const unsigned short* B = pass ? B1 : B0;
        const unsigned short* pa0 = A + (size_t)ga0 * K + kcol;
        const unsigned short* pa1 = A + (size_t)ga1 * K + kcol;
        const unsigned short* pb0 = B + (size_t)gb0 * K + kcol;
        const unsigned short* pb1 = B + (size_t)gb1 * K + kcol;
        #pragma unroll
        for (int i = 0; i < 4; i++)
            #pragma unroll
            for (int j = 0; j < 4; j++) acc[i][j] = (floatx4){0.f, 0.f, 0.f, 0.f};

        for (int kk = 0; kk < K; kk += 32) {
            GLL(pa0 + kk, la0);
            GLL(pa1 + kk, la1);
            GLL(pb0 + kk, lb0);
            GLL(pb1 + kk, lb1);
            __syncthreads();
            bf16x8 af[4], bf[4];
            #pragma unroll
            for (int mi = 0; mi < 4; mi++)
                af[mi] = *(const bf16x8*)&sA[(mbase + mi * 16) * 32 + koff];
            #pragma unroll
            for (int ni = 0; ni < 4; ni++)
                bf[ni] = *(const bf16x8*)&sB[(nbase + ni * 16) * 32 + koff];
            #pragma unroll
            for (int mi = 0; mi < 4; mi++)
                #pragma unroll
                for (int ni = 0; ni < 4; ni++)
                    acc[mi][ni] = __builtin_amdgcn_mfma_f32_16x16x32_bf16(
                        af[mi], bf[ni], acc[mi][ni], 0, 0, 0);
            __syncthreads();
        }
        if (pass == 0) {
            #pragma unroll
            for (int mi = 0; mi < 4; mi++)
                #pragma unroll
                for (int ni = 0; ni < 4; ni++)
                    #pragma unroll
                    for (int r = 0; r < 4; r++)
                        res[mi][ni][r] = fmaxf(acc[mi][ni][r], 0.0f);
        }
    }

    const int crow = bm + (wave & 1) * 64 + (lane >> 4) * 4;
    const int ccol = bn + (wave >> 1) * 64 + (lane & 15);
    #pragma unroll
    for (int mi = 0; mi < 4; mi++)
        #pragma unroll
        for (int ni = 0; ni < 4; ni++)
            #pragma unroll
            for (int r = 0; r < 4; r++) {
                int row = crow + mi * 16 + r;
                if (row >= M) continue;
                int col = ccol + ni * 16;
                float v = alpha * (res[mi][ni][r] + fmaxf(acc[mi][ni][r], 0.0f));
                size_t idx = (size_t)row * Nc + col;
                if (outF) outF[idx] = v;
                else      outH[idx] = f2b(v);
            }
}

// ---------------- host orchestration ----------------

extern "C" void kernel_launch(void* const* d_in, const int* in_sizes, int n_in,
                              void* d_out, int out_size, void* d_ws, size_t ws_size,
                              hipStream_t stream) {
    const int F = 256;
    const int N = in_sizes[0] / F;
    const int PEd = in_sizes[1] / N;          // 98
    const int E = in_sizes[2] / 2;            // 800000
    const int KC = F + PEd;                   // 354
    const int KP = (KC + 31) & ~31;           // 384

    const float* x   = (const float*)d_in[0];
    const float* pe  = (const float*)d_in[1];
    const int*   ei0 = (const int*)d_in[2];
    const float* ea0 = (const float*)d_in[3];
    const int*   ei1 = (const int*)d_in[4];
    const float* ea1 = (const float*)d_in[5];
    const float* Wn1 = (const float*)d_in[6];
    const float* Wn2 = (const float*)d_in[7];
    const float* W11 = (const float*)d_in[8];
    const float* W12 = (const float*)d_in[9];
    const float* W21 = (const float*)d_in[10];
    const float* W22 = (const float*)d_in[11];
    const float* W31 = (const float*)d_in[12];
    const float* W32 = (const float*)d_in[13];
    const float* W41 = (const float*)d_in[14];
    const float* W42 = (const float*)d_in[15];
    float* out = (float*)d_out;

    char* p = (char*)d_ws;
    auto alloc = [&](size_t b) -> char* {
        char* r = p;
        p += (b + 255) & ~(size_t)255;
        return r;
    };
    int*   cnt0  = (int*)alloc((size_t)N * 4);
    int*   cnt1  = (int*)alloc((size_t)N * 4);
    int*   tot   = (int*)alloc(2 * 4);           // bump counters (memset'd)
    int*   off0  = (int*)alloc((size_t)N * 4);
    int*   off1  = (int*)alloc((size_t)N * 4);
    int*   cur0  = (int*)alloc((size_t)N * 4);
    int*   cur1  = (int*)alloc((size_t)N * 4);
    float* dinv0 = (float*)alloc((size_t)N * 4);
    float* dinv1 = (float*)alloc((size_t)N * 4);
    uint2* rec0  = (uint2*)alloc(((size_t)E + 4ull * N) * 8);   // padded CSR
    uint2* rec1  = (uint2*)alloc(((size_t)E + 4ull * N) * 8);
    unsigned short* wn0c = (unsigned short*)alloc((size_t)F * KP * 2);
    unsigned short* wn1c = (unsigned short*)alloc((size_t)F * KP * 2);
    unsigned short* wc0  = (unsigned short*)alloc((size_t)F * 512 * 2);
    unsigned short* wc1  = (unsigned short*)alloc((size_t)F * 512 * 2);
    unsigned short* wc2  = (unsigned short*)alloc((size_t)F * 512 * 2);
    unsigned short* wc3  = (unsigned short*)alloc((size_t)F * 512 * 2);
    unsigned short* xa   = (unsigned short*)alloc((size_t)N * 512 * 2);  // xa|xb
    unsigned short* xb   = xa + (size_t)N * 256;
    unsigned short* h    = (unsigned short*)alloc((size_t)N * F * 2);
    unsigned short* a12  = (unsigned short*)alloc((size_t)N * 512 * 2);
    unsigned short* xc   = a12;                  // dead after node transforms
    unsigned short* a12bL1 = (unsigned short*)d_out;  // N*512 bf16 == out_size f32
    unsigned short* a12bL2 = xa;                 // xa|xb dead after layer-1 agg

    const int B = 256;
    const int gE = (E + B - 1) / B;
    const int gN = (N + B - 1) / B;
    const int gW = (N + 3) / 4;                  // 4 waves (nodes) per block
    const int Mb = (N + 127) / 128;
    dim3 dual_grid(2, Mb);
    dim3 bt_grid(2, 2, Mb);

    // 1. zero cnt0|cnt1|tot (contiguous span), then fused front
    hipMemsetAsync(cnt0, 0, (size_t)((char*)off0 - (char*)cnt0), stream);
    {
        const int NXC = N * (KP >> 3);
        const int TOTW = 2 * F * KP + 4 * F * 512;
        long long totThreads = 2ll * E + NXC + TOTW;
        k_front<<<(unsigned)((totThreads + B - 1) / B), B, 0, stream>>>(
            ei0 + E, ei1 + E, E, cnt0, cnt1, x, pe, xc,
            Wn1, Wn2, W11, W12, W21, W22, W31, W32, W41, W42,
            wn0c, wn1c, wc0, wc1, wc2, wc3, N, F, PEd, KC, KP);
    }

    // 2. CSR region allocation + fill
    k_alloc<<<dim3(gN, 2), B, 0, stream>>>(cnt0, cnt1, tot, off0, off1,
                                           dinv0, dinv1, cur0, cur1, N);
    k_fillpad<<<dim3(gE + gN, 2), B, 0, stream>>>(
        ei0, ea0, ei1, ea1, E, gE * B, cnt0, cnt1, off0, off1,
        dinv0, dinv1, cur0, cur1, rec0, rec1, N);

    // 3. node transforms -> xa, xb  [row-major N x 256]
    gemm_bt<<<bt_grid, B, 0, stream>>>(xc, wn0c, wn1c, N, KP, F, xa, xb);

    // 4. layer 1: both aggs in one dispatch; then dual GEMM -> h (bf16)
    k_agg<<<dim3(gW, 2), B, 0, stream>>>(xa, xb, cnt0, cnt1, off0, off1,
                                         rec0, rec1, a12, a12bL1, N);
    gemm_dual<<<dual_grid, B, 0, stream>>>(a12, wc0, a12bL1, wc1, N, 512, F,
                                           nullptr, h, 0.5f);

    // 5. layer 2: both aggs in one dispatch; then dual GEMM -> out (f32)
    k_agg<<<dim3(gW, 2), B, 0, stream>>>(h, h, cnt0, cnt1, off0, off1,
                                         rec0, rec1, a12, a12bL2, N);
    gemm_dual<<<dual_grid, B, 0, stream>>>(a12, wc2, a12bL2, wc3, N, 512, F,
                                           out, nullptr, 0.5f);
}

// Round 6
// 707.670 us; speedup vs baseline: 1.0172x; 1.0172x over previous
//
#include <hip/hip_runtime.h>

// ---------------------------------------------------------------------------
// GraphTrajSimEncoder on MI355X — round 12.
// R11 post-mortem: allocator+grid-reorder ~neutral; A-refetch was a non-cost.
// Accounting puts ~375us in the 3 GEMM dispatches -> gemm_dual likely ~100us
// each at 2 waves/SIMD (acc 64 + res 64 VGPR ~ 190 total; m132 showed this
// occupancy cliff halves GEMM perf). R12:
//  - gemm_dual: park pass-0 relu as PACKED BF16 (uint2 resp[4][4], 32 VGPR,
//    -32 vs f32 res) + __launch_bounds__(256,3) -> 3 waves/SIMD.
//    Layer-1 bit-identical (res was f2b'd anyway); layer-2 adds one bf16
//    rounding on the pass-0 term (watch absmax).
//  - gemm_bt: explicit __launch_bounds__(256,3).
//  - k_agg untouched (at the ~4.2 TB/s gather-path wall: 4 impls converged).
// ---------------------------------------------------------------------------

using bf16x8  = __attribute__((ext_vector_type(8))) __bf16;
using floatx4 = __attribute__((ext_vector_type(4))) float;
using f32x2   = __attribute__((ext_vector_type(2))) float;

__device__ __forceinline__ float b2f(unsigned short b) {
    return __uint_as_float(((unsigned)b) << 16);
}
__device__ __forceinline__ unsigned short f2b(float f) {
    unsigned u = __float_as_uint(f);
    return (unsigned short)((u + 0x7FFFu + ((u >> 16) & 1u)) >> 16);
}
__device__ __forceinline__ unsigned short f2h(float f) {
    _Float16 h = (_Float16)f;
    return __builtin_bit_cast(unsigned short, h);
}
__device__ __forceinline__ float h2f(unsigned short u) {
    return (float)__builtin_bit_cast(_Float16, u);
}

// ---------------- fused front kernel ----------------
// segment 0: [0, E)            set-0 degree count atomics
// segment 1: [E, 2E)           set-1 degree count atomics
// segment 2: [2E, 2E+NXC)      xc bf16 conversion, 8 elems/thread
// segment 3: [.., +TOTW)       weight conversions
__global__ void k_front(
    const int* __restrict__ col0, const int* __restrict__ col1, int E,
    int* __restrict__ cnt0, int* __restrict__ cnt1,
    const float* __restrict__ x, const float* __restrict__ pe,
    unsigned short* __restrict__ xc,
    const float* __restrict__ Wn1, const float* __restrict__ Wn2,
    const float* __restrict__ W11, const float* __restrict__ W12,
    const float* __restrict__ W21, const float* __restrict__ W22,
    const float* __restrict__ W31, const float* __restrict__ W32,
    const float* __restrict__ W41, const float* __restrict__ W42,
    unsigned short* __restrict__ wn0c, unsigned short* __restrict__ wn1c,
    unsigned short* __restrict__ wc0, unsigned short* __restrict__ wc1,
    unsigned short* __restrict__ wc2, unsigned short* __restrict__ wc3,
    int n, int F, int PEd, int KC, int KP) {
    int idx = blockIdx.x * 256 + threadIdx.x;
    if (idx < E) { atomicAdd(&cnt0[col0[idx]], 1); return; }
    idx -= E;
    if (idx < E) { atomicAdd(&cnt1[col1[idx]], 1); return; }
    idx -= E;
    const int CH = KP >> 3;
    const int NXC = n * CH;
    if (idx < NXC) {
        int i = idx / CH, c = idx - i * CH;
        int k = c << 3;
        uint4 o;
        if (k + 8 <= F) {
            const float4* px = (const float4*)(x + (size_t)i * F + k);
            float4 v0 = px[0];
            float4 v1 = px[1];
            o.x = (unsigned)f2b(v0.x) | ((unsigned)f2b(v0.y) << 16);
            o.y = (unsigned)f2b(v0.z) | ((unsigned)f2b(v0.w) << 16);
            o.z = (unsigned)f2b(v1.x) | ((unsigned)f2b(v1.y) << 16);
            o.w = (unsigned)f2b(v1.z) | ((unsigned)f2b(v1.w) << 16);
        } else if (k < KC) {
            const float* pp = pe + (size_t)i * PEd + (k - F);
            int rem = KC - k;
            float e0 = pp[0];
            float e1 = (1 < rem) ? pp[1] : 0.f;
            float e2 = (2 < rem) ? pp[2] : 0.f;
            float e3 = (3 < rem) ? pp[3] : 0.f;
            float e4 = (4 < rem) ? pp[4] : 0.f;
            float e5 = (5 < rem) ? pp[5] : 0.f;
            float e6 = (6 < rem) ? pp[6] : 0.f;
            float e7 = (7 < rem) ? pp[7] : 0.f;
            o.x = (unsigned)f2b(e0) | ((unsigned)f2b(e1) << 16);
            o.y = (unsigned)f2b(e2) | ((unsigned)f2b(e3) << 16);
            o.z = (unsigned)f2b(e4) | ((unsigned)f2b(e5) << 16);
            o.w = (unsigned)f2b(e6) | ((unsigned)f2b(e7) << 16);
        } else {
            o.x = o.y = o.z = o.w = 0u;
        }
        *(uint4*)(xc + (size_t)idx * 8) = o;
        return;
    }
    idx -= NXC;
    int npad = F * KP;
    if (idx < 2 * npad) {
        const float* W = (idx < npad) ? Wn1 : Wn2;
        unsigned short* Wc = (idx < npad) ? wn0c : wn1c;
        int t = (idx < npad) ? idx : idx - npad;
        int o = t / KP, k = t - o * KP;
        Wc[t] = f2b(k < KC ? W[(size_t)o * KC + k] : 0.0f);
        return;
    }
    int t = idx - 2 * npad;
    int seg = F * 512;
    if (t >= 4 * seg) return;
    int which = t / seg;
    int r = t - which * seg;
    const float* Wa = (which == 0) ? W11 : (which == 1) ? W21 : (which == 2) ? W31 : W41;
    const float* Wb = (which == 0) ? W12 : (which == 1) ? W22 : (which == 2) ? W32 : W42;
    unsigned short* Wc = (which == 0) ? wc0 : (which == 1) ? wc1 : (which == 2) ? wc2 : wc3;
    int o = r >> 9, k = r & 511;
    float v = (k < 256) ? Wa[(size_t)o * 256 + k] : Wb[(size_t)o * 256 + (k - 256)];
    Wc[r] = f2b(v);
}

// ---------------- CSR region allocation (bump allocator) ----------------
__global__ void k_alloc(
    const int* __restrict__ cnt0, const int* __restrict__ cnt1,
    int* __restrict__ tot,                       // tot[0], tot[1] zeroed
    int* __restrict__ off0, int* __restrict__ off1,
    float* __restrict__ dinv0, float* __restrict__ dinv1,
    int* __restrict__ cur0, int* __restrict__ cur1, int n) {
    int i = blockIdx.x * 256 + threadIdx.x;
    if (i >= n) return;
    const int* cnt = blockIdx.y ? cnt1 : cnt0;
    int* off = blockIdx.y ? off1 : off0;
    float* dinv = blockIdx.y ? dinv1 : dinv0;
    int* cur = blockIdx.y ? cur1 : cur0;
    int ci = cnt[i];
    int pad = (ci + 4) & ~3;
    int o = atomicAdd(&tot[blockIdx.y], pad);
    off[i] = o;
    cur[i] = o;
    dinv[i] = rsqrtf((float)(ci + 1));
}

// Fused CSR fill + self-loop/pad. Threads [0, EB) fill edges; [EB, EB+n) pad.
// Edge record: (src:u32, (fp16 w1)<<16 | fp16 w2). Self: w1=dinv^2, w2=1.
__global__ void k_fillpad(
    const int* __restrict__ ei0, const float* __restrict__ ea0,
    const int* __restrict__ ei1, const float* __restrict__ ea1,
    int E, int EB,
    const int* __restrict__ cnt0, const int* __restrict__ cnt1,
    const int* __restrict__ off0, const int* __restrict__ off1,
    const float* __restrict__ dinv0, const float* __restrict__ dinv1,
    int* __restrict__ cur0, int* __restrict__ cur1,
    uint2* __restrict__ rec0, uint2* __restrict__ rec1, int n) {
    const int s = blockIdx.y;
    const float* dinv = s ? dinv1 : dinv0;
    uint2* rec = s ? rec1 : rec0;
    int t = blockIdx.x * 256 + threadIdx.x;
    if (t < EB) {
        int e = t;
        if (e >= E) return;
        const int* ei = s ? ei1 : ei0;
        const float* ea = s ? ea1 : ea0;
        int* cur = s ? cur1 : cur0;
        int r = ei[e];          // source
        int c = ei[E + e];      // target
        float a = ea[e];
        float w2 = (a > 0.0f) ? fminf(rsqrtf(a), 1.0f) : 0.0f;
        float w1 = dinv[r] * dinv[c];
        int p = atomicAdd(&cur[c], 1);
        rec[p] = make_uint2((unsigned)r,
                            ((unsigned)f2h(w1) << 16) | (unsigned)f2h(w2));
    } else {
        int i = t - EB;
        if (i >= n) return;
        const int* cnt = s ? cnt1 : cnt0;
        const int* off = s ? off1 : off0;
        int ci = cnt[i];
        int p = off[i] + ci, pe = off[i] + ((ci + 4) & ~3);
        float di = dinv[i];
        rec[p++] = make_uint2((unsigned)i,
                              ((unsigned)f2h(di * di) << 16) | 0x3C00u);  // w2=1
        for (; p < pe; ++p) rec[p] = make_uint2(0u, 0u);
    }
}

// ---------------- CSR gather-aggregation v6 (unchanged, at its wall) --------

#define AGG4(g, wsel)                                                         \
    do {                                                                      \
        float w1 = h2f((unsigned short)((wsel) >> 16));                       \
        float w2 = h2f((unsigned short)((wsel) & 0xFFFFu));                   \
        f32x2 w1v = {w1, w1};                                                 \
        f32x2 w2v = {w2, w2};                                                 \
        f32x2 v;                                                              \
        v.x = __uint_as_float((g).x << 16);                                   \
        v.y = __uint_as_float((g).x & 0xFFFF0000u);                           \
        c1a = __builtin_elementwise_fma(w1v, v, c1a);                         \
        c2a = __builtin_elementwise_fma(w2v, v, c2a);                         \
        v.x = __uint_as_float((g).y << 16);                                   \
        v.y = __uint_as_float((g).y & 0xFFFF0000u);                           \
        c1b = __builtin_elementwise_fma(w1v, v, c1b);                         \
        c2b = __builtin_elementwise_fma(w2v, v, c2b);                         \
    } while (0)

__global__ __launch_bounds__(256) void k_agg(
    const unsigned short* __restrict__ X0, const unsigned short* __restrict__ X1,
    const int* __restrict__ cnt0, const int* __restrict__ cnt1,
    const int* __restrict__ off0, const int* __restrict__ off1,
    const uint2* __restrict__ rec0, const uint2* __restrict__ rec1,
    unsigned short* __restrict__ A0, unsigned short* __restrict__ A1, int n) {
    const int s = blockIdx.y;
    const unsigned short* X = s ? X1 : X0;
    const int* cnt = s ? cnt1 : cnt0;
    const int* off = s ? off1 : off0;
    const uint2* rec = s ? rec1 : rec0;
    unsigned short* A = s ? A1 : A0;

    const int gw = (blockIdx.x * 256 + threadIdx.x) >> 6;
    const int lane = threadIdx.x & 63;
    if (gw >= n) return;

    const int e0 = __builtin_amdgcn_readfirstlane(off[gw]);
    const int cv = __builtin_amdgcn_readfirstlane(cnt[gw]);
    const uint2* X2 = (const uint2*)X;          // 4 bf16 per lane-chunk

    f32x2 c1a = {0.f, 0.f}, c1b = {0.f, 0.f};
    f32x2 c2a = {0.f, 0.f}, c2b = {0.f, 0.f};

    const uint4* recq = (const uint4*)(rec + e0);   // 1 uint4 = 2 records
    const int nit = ((cv + 4) & ~3) >> 2;           // 4 records / iter, >= 1
    #pragma unroll 2
    for (int it = 0; it < nit; ++it) {
        uint4 qa = recq[it * 2];
        uint4 qb = recq[it * 2 + 1];
        unsigned s0 = (unsigned)__builtin_amdgcn_readfirstlane(qa.x);
        unsigned s1 = (unsigned)__builtin_amdgcn_readfirstlane(qa.z);
        unsigned s2 = (unsigned)__builtin_amdgcn_readfirstlane(qb.x);
        unsigned s3 = (unsigned)__builtin_amdgcn_readfirstlane(qb.z);
        uint2 g0 = X2[(size_t)s0 * 64 + lane];
        uint2 g1 = X2[(size_t)s1 * 64 + lane];
        uint2 g2 = X2[(size_t)s2 * 64 + lane];
        uint2 g3 = X2[(size_t)s3 * 64 + lane];
        AGG4(g0, qa.y);
        AGG4(g1, qa.w);
        AGG4(g2, qb.y);
        AGG4(g3, qb.w);
    }

    uint2 o1, o2;
    o1.x = (unsigned)f2b(c1a.x) | ((unsigned)f2b(c1a.y) << 16);
    o1.y = (unsigned)f2b(c1b.x) | ((unsigned)f2b(c1b.y) << 16);
    o2.x = (unsigned)f2b(c2a.x) | ((unsigned)f2b(c2a.y) << 16);
    o2.y = (unsigned)f2b(c2b.x) | ((unsigned)f2b(c2b.y) << 16);
    *(uint2*)(A + (size_t)gw * 512 + lane * 4) = o1;
    *(uint2*)(A + (size_t)gw * 512 + 256 + lane * 4) = o2;
}

// ---------------- bf16 MFMA GEMM kernels ----------------
#define GLL(g, l) \
    __builtin_amdgcn_global_load_lds((__attribute__((address_space(1))) void*)(g), \
                                     (__attribute__((address_space(3))) void*)(l), 16, 0, 0)

// node-transform GEMM: C[M][Nc] = A[M][K] @ B[Nc][K]^T, bf16 out.
// Grid (2, 2, Mb): x = column tile, y = B/out select, z = row tile.
__global__ __launch_bounds__(256, 3) void gemm_bt(
    const unsigned short* __restrict__ A,
    const unsigned short* __restrict__ B0, const unsigned short* __restrict__ B1,
    int M, int K, int Nc,
    unsigned short* __restrict__ outH0, unsigned short* __restrict__ outH1) {
    const unsigned short* B = blockIdx.y ? B1 : B0;
    unsigned short* outH = blockIdx.y ? outH1 : outH0;

    __shared__ __align__(16) unsigned short sA[128 * 32];
    __shared__ __align__(16) unsigned short sB[128 * 32];
    const int tid = threadIdx.x;
    const int lane = tid & 63;
    const int wave = tid >> 6;
    const int bm = blockIdx.z * 128;
    const int bn = blockIdx.x * 128;

    const int r0 = wave * 32 + (lane >> 2);
    const int kcol = (lane & 3) * 8;
    const int ga0 = min(bm + r0, M - 1);
    const int ga1 = min(bm + r0 + 16, M - 1);
    const int gb0 = min(bn + r0, Nc - 1);
    const int gb1 = min(bn + r0 + 16, Nc - 1);
    const unsigned short* pa0 = A + (size_t)ga0 * K + kcol;
    const unsigned short* pa1 = A + (size_t)ga1 * K + kcol;
    const unsigned short* pb0 = B + (size_t)gb0 * K + kcol;
    const unsigned short* pb1 = B + (size_t)gb1 * K + kcol;
    unsigned short* la0 = &sA[wave * 1024];
    unsigned short* la1 = &sA[wave * 1024 + 512];
    unsigned short* lb0 = &sB[wave * 1024];
    unsigned short* lb1 = &sB[wave * 1024 + 512];

    floatx4 acc[4][4];
    #pragma unroll
    for (int i = 0; i < 4; i++)
        #pragma unroll
        for (int j = 0; j < 4; j++) acc[i][j] = (floatx4){0.f, 0.f, 0.f, 0.f};

    const int mbase = (wave & 1) * 64 + (lane & 15);
    const int nbase = (wave >> 1) * 64 + (lane & 15);
    const int koff = (lane >> 4) * 8;

    for (int kk = 0; kk < K; kk += 32) {
        GLL(pa0 + kk, la0);
        GLL(pa1 + kk, la1);
        GLL(pb0 + kk, lb0);
        GLL(pb1 + kk, lb1);
        __syncthreads();
        bf16x8 af[4], bf[4];
        #pragma unroll
        for (int mi = 0; mi < 4; mi++)
            af[mi] = *(const bf16x8*)&sA[(mbase + mi * 16) * 32 + koff];
        #pragma unroll
        for (int ni = 0; ni < 4; ni++)
            bf[ni] = *(const bf16x8*)&sB[(nbase + ni * 16) * 32 + koff];
        #pragma unroll
        for (int mi = 0; mi < 4; mi++)
            #pragma unroll
            for (int ni = 0; ni < 4; ni++)
                acc[mi][ni] = __builtin_amdgcn_mfma_f32_16x16x32_bf16(
                    af[mi], bf[ni], acc[mi][ni], 0, 0, 0);
        __syncthreads();
    }

    const int crow = bm + (wave & 1) * 64 + (lane >> 4) * 4;
    const int ccol = bn + (wave >> 1) * 64 + (lane & 15);
    #pragma unroll
    for (int mi = 0; mi < 4; mi++)
        #pragma unroll
        for (int ni = 0; ni < 4; ni++)
            #pragma unroll
            for (int r = 0; r < 4; r++) {
                int row = crow + mi * 16 + r;
                if (row >= M) continue;
                int col = ccol + ni * 16;
                outH[(size_t)row * Nc + col] = f2b(acc[mi][ni][r]);
            }
}

// dual GEMM: C = 0.5*relu(A0@B0^T) + 0.5*relu(A1@B1^T); out f32 or bf16.
// Grid (2, Mb). Pass-0 relu parked as PACKED BF16 (32 VGPR) -> 3 waves/SIMD.
__global__ __launch_bounds__(256, 3) void gemm_dual(
    const unsigned short* __restrict__ A0, const unsigned short* __restrict__ B0,
    const unsigned short* __restrict__ A1, const unsigned short* __restrict__ B1,
    int M, int K, int Nc,
    float* __restrict__ outF, unsigned short* __restrict__ outH, float alpha) {
    __shared__ __align__(16) unsigned short sA[128 * 32];
    __shared__ __align__(16) unsigned short sB[128 * 32];
    const int tid = threadIdx.x;
    const int lane = tid & 63;
    const int wave = tid >> 6;
    const int bm = blockIdx.y * 128;
    const int bn = blockIdx.x * 128;

    const int r0 = wave * 32 + (lane >> 2);
    const int kcol = (lane & 3) * 8;
    const int ga0 = min(bm + r0, M - 1);
    const int ga1 = min(bm + r0 + 16, M - 1);
    const int gb0 = min(bn + r0, Nc - 1);
    const int gb1 = min(bn + r0 + 16, Nc - 1);
    unsigned short* la0 = &sA[wave * 1024];
    unsigned short* la1 = &sA[wave * 1024 + 512];
    unsigned short* lb0 = &sB[wave * 1024];
    unsigned short* lb1 = &sB[wave * 1024 + 512];

    const int mbase = (wave & 1) * 64 + (lane & 15);
    const int nbase = (wave >> 1) * 64 + (lane & 15);
    const int koff = (lane >> 4) * 8;

    floatx4 acc[4][4];
    uint2 resp[4][4];                    // packed bf16 relu(pass0), 32 VGPR

    #pragma unroll
    for (int pass = 0; pass < 2; pass++) {
        const unsigned short* A = pass ? A1 : A0;
        const unsigned short* B = pass ? B1 : B0;
        const unsigned short* pa0 = A + (size_t)ga0 * K + kcol;
        const unsigned short* pa1 = A + (size_t)ga1 * K + kcol;
        const unsigned short* pb0 = B + (size_t)gb0 * K + kcol;
        const unsigned short* pb1 = B + (size_t)gb1 * K + kcol;
        #pragma unroll
        for (int i = 0; i < 4; i++)
            #pragma unroll
            for (int j = 0; j < 4; j++) acc[i][j] = (floatx4){0.f, 0.f, 0.f, 0.f};

        for (int kk = 0; kk < K; kk += 32) {
            GLL(pa0 + kk, la0);
            GLL(pa1 + kk, la1);
            GLL(pb0 + kk, lb0);
            GLL(pb1 + kk, lb1);
            __syncthreads();
            bf16x8 af[4], bf[4];
            #pragma unroll
            for (int mi = 0; mi < 4; mi++)
                af[mi] = *(const bf16x8*)&sA[(mbase + mi * 16) * 32 + koff];
            #pragma unroll
            for (int ni = 0; ni < 4; ni++)
                bf[ni] = *(const bf16x8*)&sB[(nbase + ni * 16) * 32 + koff];
            #pragma unroll
            for (int mi = 0; mi < 4; mi++)
                #pragma unroll
                for (int ni = 0; ni < 4; ni++)
                    acc[mi][ni] = __builtin_amdgcn_mfma_f32_16x16x32_bf16(
                        af[mi], bf[ni], acc[mi][ni], 0, 0, 0);
            __syncthreads();
        }
        if (pass == 0) {
            #pragma unroll
            for (int mi = 0; mi < 4; mi++)
                #pragma unroll
                for (int ni = 0; ni < 4; ni++) {
                    float r0f = fmaxf(acc[mi][ni][0], 0.0f);
                    float r1f = fmaxf(acc[mi][ni][1], 0.0f);
                    float r2f = fmaxf(acc[mi][ni][2], 0.0f);
                    float r3f = fmaxf(acc[mi][ni][3], 0.0f);
                    resp[mi][ni].x = (unsigned)f2b(r0f) | ((unsigned)f2b(r1f) << 16);
                    resp[mi][ni].y = (unsigned)f2b(r2f) | ((unsigned)f2b(r3f) << 16);
                }
        }
    }

    const int crow = bm + (wave & 1) * 64 + (lane >> 4) * 4;
    const int ccol = bn + (wave >> 1) * 64 + (lane & 15);
    #pragma unroll
    for (int mi = 0; mi < 4; mi++)
        #pragma unroll
        for (int ni = 0; ni < 4; ni++) {
            float p0 = b2f((unsigned short)(resp[mi][ni].x & 0xFFFFu));
            float p1 = b2f((unsigned short)(resp[mi][ni].x >> 16));
            float p2 = b2f((unsigned short)(resp[mi][ni].y & 0xFFFFu));
            float p3 = b2f((unsigned short)(resp[mi][ni].y >> 16));
            #pragma unroll
            for (int r = 0; r < 4; r++) {
                int row = crow + mi * 16 + r;
                if (row >= M) continue;
                int col = ccol + ni * 16;
                float pr = (r == 0) ? p0 : (r == 1) ? p1 : (r == 2) ? p2 : p3;
                float v = alpha * (pr + fmaxf(acc[mi][ni][r], 0.0f));
                size_t idx = (size_t)row * Nc + col;
                if (outF) outF[idx] = v;
                else      outH[idx] = f2b(v);
            }
        }
}

// ---------------- host orchestration ----------------

extern "C" void kernel_launch(void* const* d_in, const int* in_sizes, int n_in,
                              void* d_out, int out_size, void* d_ws, size_t ws_size,
                              hipStream_t stream) {
    const int F = 256;
    const int N = in_sizes[0] / F;
    const int PEd = in_sizes[1] / N;          // 98
    const int E = in_sizes[2] / 2;            // 800000
    const int KC = F + PEd;                   // 354
    const int KP = (KC + 31) & ~31;           // 384

    const float* x   = (const float*)d_in[0];
    const float* pe  = (const float*)d_in[1];
    const int*   ei0 = (const int*)d_in[2];
    const float* ea0 = (const float*)d_in[3];
    const int*   ei1 = (const int*)d_in[4];
    const float* ea1 = (const float*)d_in[5];
    const float* Wn1 = (const float*)d_in[6];
    const float* Wn2 = (const float*)d_in[7];
    const float* W11 = (const float*)d_in[8];
    const float* W12 = (const float*)d_in[9];
    const float* W21 = (const float*)d_in[10];
    const float* W22 = (const float*)d_in[11];
    const float* W31 = (const float*)d_in[12];
    const float* W32 = (const float*)d_in[13];
    const float* W41 = (const float*)d_in[14];
    const float* W42 = (const float*)d_in[15];
    float* out = (float*)d_out;

    char* p = (char*)d_ws;
    auto alloc = [&](size_t b) -> char* {
        char* r = p;
        p += (b + 255) & ~(size_t)255;
        return r;
    };
    int*   cnt0  = (int*)alloc((size_t)N * 4);
    int*   cnt1  = (int*)alloc((size_t)N * 4);
    int*   tot   = (int*)alloc(2 * 4);           // bump counters (memset'd)
    int*   off0  = (int*)alloc((size_t)N * 4);
    int*   off1  = (int*)alloc((size_t)N * 4);
    int*   cur0  = (int*)alloc((size_t)N * 4);
    int*   cur1  = (int*)alloc((size_t)N * 4);
    float* dinv0 = (float*)alloc((size_t)N * 4);
    float* dinv1 = (float*)alloc((size_t)N * 4);
    uint2* rec0  = (uint2*)alloc(((size_t)E + 4ull * N) * 8);   // padded CSR
    uint2* rec1  = (uint2*)alloc(((size_t)E + 4ull * N) * 8);
    unsigned short* wn0c = (unsigned short*)alloc((size_t)F * KP * 2);
    unsigned short* wn1c = (unsigned short*)alloc((size_t)F * KP * 2);
    unsigned short* wc0  = (unsigned short*)alloc((size_t)F * 512 * 2);
    unsigned short* wc1  = (unsigned short*)alloc((size_t)F * 512 * 2);
    unsigned short* wc2  = (unsigned short*)alloc((size_t)F * 512 * 2);
    unsigned short* wc3  = (unsigned short*)alloc((size_t)F * 512 * 2);
    unsigned short* xa   = (unsigned short*)alloc((size_t)N * 512 * 2);  // xa|xb
    unsigned short* xb   = xa + (size_t)N * 256;
    unsigned short* h    = (unsigned short*)alloc((size_t)N * F * 2);
    unsigned short* a12  = (unsigned short*)alloc((size_t)N * 512 * 2);
    unsigned short* xc   = a12;                  // dead after node transforms
    unsigned short* a12bL1 = (unsigned short*)d_out;  // N*512 bf16 == out_size f32
    unsigned short* a12bL2 = xa;                 // xa|xb dead after layer-1 agg

    const int B = 256;
    const int gE = (E + B - 1) / B;
    const int gN = (N + B - 1) / B;
    const int gW = (N + 3) / 4;                  // 4 waves (nodes) per block
    const int Mb = (N + 127) / 128;
    dim3 dual_grid(2, Mb);
    dim3 bt_grid(2, 2, Mb);

    // 1. zero cnt0|cnt1|tot (contiguous span), then fused front
    hipMemsetAsync(cnt0, 0, (size_t)((char*)off0 - (char*)cnt0), stream);
    {
        const int NXC = N * (KP >> 3);
        const int TOTW = 2 * F * KP + 4 * F * 512;
        long long totThreads = 2ll * E + NXC + TOTW;
        k_front<<<(unsigned)((totThreads + B - 1) / B), B, 0, stream>>>(
            ei0 + E, ei1 + E, E, cnt0, cnt1, x, pe, xc,
            Wn1, Wn2, W11, W12, W21, W22, W31, W32, W41, W42,
            wn0c, wn1c, wc0, wc1, wc2, wc3, N, F, PEd, KC, KP);
    }

    // 2. CSR region allocation + fill
    k_alloc<<<dim3(gN, 2), B, 0, stream>>>(cnt0, cnt1, tot, off0, off1,
                                           dinv0, dinv1, cur0, cur1, N);
    k_fillpad<<<dim3(gE + gN, 2), B, 0, stream>>>(
        ei0, ea0, ei1, ea1, E, gE * B, cnt0, cnt1, off0, off1,
        dinv0, dinv1, cur0, cur1, rec0, rec1, N);

    // 3. node transforms -> xa, xb  [row-major N x 256]
    gemm_bt<<<bt_grid, B, 0, stream>>>(xc, wn0c, wn1c, N, KP, F, xa, xb);

    // 4. layer 1: both aggs in one dispatch; then dual GEMM -> h (bf16)
    k_agg<<<dim3(gW, 2), B, 0, stream>>>(xa, xb, cnt0, cnt1, off0, off1,
                                         rec0, rec1, a12, a12bL1, N);
    gemm_dual<<<dual_grid, B, 0, stream>>>(a12, wc0, a12bL1, wc1, N, 512, F,
                                           nullptr, h, 0.5f);

    // 5. layer 2: both aggs in one dispatch; then dual GEMM -> out (f32)
    k_agg<<<dim3(gW, 2), B, 0, stream>>>(h, h, cnt0, cnt1, off0, off1,
                                         rec0, rec1, a12, a12bL2, N);
    gemm_dual<<<dual_grid, B, 0, stream>>>(a12, wc2, a12bL2, wc3, N, 512, F,
                                           out, nullptr, 0.5f);
}